// Round 2
// baseline (4084.469 us; speedup 1.0000x reference)
//
#include <hip/hip_runtime.h>
#include <stdint.h>

#define LCOUNT 6
#define BB 4
#define SS 2048
#define DD 512
#define HH 8
#define DKK 64
#define FFDIM 2048
#define MM (BB*SS)  // 8192 rows

typedef __attribute__((ext_vector_type(8))) __bf16 bf16x8;
typedef __attribute__((ext_vector_type(4))) float f32x4;
typedef unsigned short u16;

__device__ __forceinline__ u16 f2bf(float f) {
  union { float f; uint32_t u; } v; v.f = f;
  uint32_t r = v.u + 0x7FFFu + ((v.u >> 16) & 1u);
  return (u16)(r >> 16);
}
__device__ __forceinline__ float bf2f(u16 u) {
  union { uint32_t u; float f; } v; v.u = ((uint32_t)u) << 16;
  return v.f;
}

__device__ __forceinline__ void gload_lds16(const u16* gsrc, u16* ldst) {
  __builtin_amdgcn_global_load_lds((const __attribute__((address_space(1))) char*)gsrc,
                                   (__attribute__((address_space(3))) char*)ldst, 16, 0, 0);
}

// ---------------------------------------------------------------------------
// fp32 -> bf16 elementwise convert (n divisible by 8)
__global__ __launch_bounds__(256) void f2bf_kernel(const float* __restrict__ in,
                                                   u16* __restrict__ outp, int n) {
  int i = (blockIdx.x * 256 + threadIdx.x) * 8;
  if (i >= n) return;
  float4 a = *(const float4*)&in[i];
  float4 b = *(const float4*)&in[i + 4];
  union { u16 us[8]; uint4 v; } pk;
  pk.us[0] = f2bf(a.x); pk.us[1] = f2bf(a.y); pk.us[2] = f2bf(a.z); pk.us[3] = f2bf(a.w);
  pk.us[4] = f2bf(b.x); pk.us[5] = f2bf(b.y); pk.us[6] = f2bf(b.z); pk.us[7] = f2bf(b.w);
  *(uint4*)&outp[i] = pk.v;
}

// ---------------------------------------------------------------------------
// W [K][N] fp32  ->  Wt [N][K] bf16   (per layer, blockIdx.z = layer)
__global__ __launch_bounds__(256) void wtrans(const float* __restrict__ W,
                                              u16* __restrict__ Wt, int K_, int N_) {
  __shared__ float tile[64 * 65];
  const int l = blockIdx.z;
  const float* Wl = W + (size_t)l * K_ * N_;
  u16* Wtl = Wt + (size_t)l * K_ * N_;
  const int n0 = blockIdx.x * 64, k0 = blockIdx.y * 64;
  const int tid = threadIdx.x;
  const int r = tid >> 2, c4 = (tid & 3) * 16;
#pragma unroll
  for (int j = 0; j < 16; j += 4) {
    float4 v = *(const float4*)&Wl[(size_t)(k0 + r) * N_ + n0 + c4 + j];
    tile[r * 65 + c4 + j + 0] = v.x;
    tile[r * 65 + c4 + j + 1] = v.y;
    tile[r * 65 + c4 + j + 2] = v.z;
    tile[r * 65 + c4 + j + 3] = v.w;
  }
  __syncthreads();
  const int nr = tid >> 2, kc = (tid & 3) * 16;
#pragma unroll
  for (int half = 0; half < 2; ++half) {
    union { u16 us[8]; uint4 v; } pk;
#pragma unroll
    for (int e = 0; e < 8; ++e) pk.us[e] = f2bf(tile[(kc + half * 8 + e) * 65 + nr]);
    *(uint4*)&Wtl[(size_t)(n0 + nr) * K_ + k0 + kc + half * 8] = pk.v;
  }
}

// ---------------------------------------------------------------------------
// V [B*S][D] bf16 (head h cols h*64..h*64+63)  ->  Vt [B][H][DK][S] bf16
// One block per (s-tile 64, h, b). XOR-swizzled 16B slots in LDS; all LDS
// phases conflict-free (<=2-way).
__global__ __launch_bounds__(256)
void vtrans(const u16* __restrict__ V, u16* __restrict__ Vt) {
  __shared__ u16 tile[64 * 64];
  const int st = blockIdx.x, h = blockIdx.y, b = blockIdx.z;
  const int tid = threadIdx.x;
  // phase 1: load 64 s-rows x 64 d-cols, 16B chunks, slot ^= row&7
  const int s_r = tid & 63;
#pragma unroll
  for (int j = 0; j < 2; ++j) {
    int chunk = (tid >> 6) + 4 * j;
    int slot = chunk ^ (s_r & 7);
    uint4 v = *(const uint4*)&V[(size_t)(b * SS + st * 64 + s_r) * DD + h * DKK + chunk * 8];
    *(uint4*)&tile[s_r * 64 + slot * 8] = v;
  }
  __syncthreads();
  // phase 2: lane d = tid&63, s-chunk sc = tid>>6; gather 16 u16 down s, store 2x16B
  const int d = tid & 63, sc = tid >> 6;
  union { u16 us[16]; uint4 v[2]; } pk;
#pragma unroll
  for (int e = 0; e < 16; ++e) {
    int s = sc * 16 + e;
    pk.us[e] = tile[s * 64 + (((d >> 3) ^ (s & 7)) * 8) + (d & 7)];
  }
  u16* dst = &Vt[((size_t)(b * HH + h) * DKK + d) * SS + st * 64 + sc * 16];
  *(uint4*)&dst[0] = pk.v[0];
  *(uint4*)&dst[8] = pk.v[1];
}

// ---------------------------------------------------------------------------
// GEMM: C[M,N] = A[M,K] @ W[K,N] + bias, W given transposed Wt[N][K].
template <int BMT, bool RELU>
__global__ __launch_bounds__(256)
void gemm_bt(const u16* __restrict__ A, const u16* __restrict__ Bt,
             const float* __restrict__ bias, u16* __restrict__ C,
             int N_, int K_) {
  constexpr int MR = BMT / 32;  // m-fragments per wave
  __shared__ u16 As[BMT * 64];
  __shared__ u16 Bs[128 * 64];
  const int tid = threadIdx.x;
  const int wid = tid >> 6, lane = tid & 63;
  const int l15 = lane & 15, g = lane >> 4;
  const int wr = wid >> 1, wc = wid & 1;
  const int brow = blockIdx.y * BMT;
  const int bcol = blockIdx.x * 128;

  f32x4 acc[MR][4];
#pragma unroll
  for (int m = 0; m < MR; ++m)
#pragma unroll
    for (int n = 0; n < 4; ++n) acc[m][n] = (f32x4){0.f, 0.f, 0.f, 0.f};

  for (int kt = 0; kt < K_; kt += 64) {
#pragma unroll
    for (int r = 0; r < BMT / 32; ++r) {
      int row = r * 32 + wid * 8 + (lane >> 3);
      int slot = (lane & 7) ^ (row & 7);
      gload_lds16(A + (size_t)(brow + row) * K_ + kt + slot * 8,
                  &As[r * 2048 + wid * 512]);
    }
#pragma unroll
    for (int r = 0; r < 4; ++r) {
      int row = r * 32 + wid * 8 + (lane >> 3);
      int slot = (lane & 7) ^ (row & 7);
      gload_lds16(Bt + (size_t)(bcol + row) * K_ + kt + slot * 8,
                  &Bs[r * 2048 + wid * 512]);
    }
    __syncthreads();
#pragma unroll
    for (int ks = 0; ks < 2; ++ks) {
      bf16x8 af[MR], bfr[4];
#pragma unroll
      for (int m = 0; m < MR; ++m) {
        int row = wr * (BMT / 2) + m * 16 + l15;
        int slot = (ks * 4 + g) ^ (row & 7);
        af[m] = *(const bf16x8*)&As[row * 64 + slot * 8];
      }
#pragma unroll
      for (int n = 0; n < 4; ++n) {
        int row = wc * 64 + n * 16 + l15;
        int slot = (ks * 4 + g) ^ (row & 7);
        bfr[n] = *(const bf16x8*)&Bs[row * 64 + slot * 8];
      }
#pragma unroll
      for (int m = 0; m < MR; ++m)
#pragma unroll
        for (int n = 0; n < 4; ++n)
          acc[m][n] = __builtin_amdgcn_mfma_f32_16x16x32_bf16(af[m], bfr[n], acc[m][n], 0, 0, 0);
    }
    __syncthreads();
  }
#pragma unroll
  for (int n = 0; n < 4; ++n) {
    int col = bcol + wc * 64 + n * 16 + l15;
    float bv = bias ? bias[col] : 0.f;
#pragma unroll
    for (int m = 0; m < MR; ++m) {
#pragma unroll
      for (int r = 0; r < 4; ++r) {
        int rowg = brow + wr * (BMT / 2) + m * 16 + g * 4 + r;
        float v = acc[m][n][r] + bv;
        if (RELU) v = fmaxf(v, 0.f);
        C[(size_t)rowg * N_ + col] = f2bf(v);
      }
    }
  }
}

// ---------------------------------------------------------------------------
// Flash attention, barrier-free. One block per (qblock=64, head, batch), 4 waves;
// wave w owns q-rows [16w,16w+16) end-to-end. Softmax in registers via 16-lane
// shfl_xor reduce. P transposed C-layout -> A-frag via per-wave LDS (pad 72,
// conflict-free). K direct from global; V from pre-transposed Vt[b][h][d][s].
template <bool CAUSAL>
__global__ __launch_bounds__(256)
void attn_kernel(const u16* __restrict__ Qm, const u16* __restrict__ Km,
                 const u16* __restrict__ Vt, u16* __restrict__ Om) {
  __shared__ u16 Ps[4][16 * 72];
  const int qb = blockIdx.x, h = blockIdx.y, b = blockIdx.z;
  const int tid = threadIdx.x, wid = tid >> 6, lane = tid & 63;
  const int l15 = lane & 15, g = lane >> 4;
  const int qstart = qb * 64;
  const size_t base = ((size_t)b * SS) * DD + h * DKK;
  const size_t vtbase = (size_t)(b * HH + h) * DKK * SS;
  u16* psw = &Ps[wid][0];

  bf16x8 qf[2];
#pragma unroll
  for (int ks = 0; ks < 2; ++ks)
    qf[ks] = *(const bf16x8*)&Qm[base + (size_t)(qstart + wid * 16 + l15) * DD + ks * 32 + g * 8];

  f32x4 oacc[4];
#pragma unroll
  for (int nb = 0; nb < 4; ++nb) oacc[nb] = (f32x4){0.f, 0.f, 0.f, 0.f};
  float m_run[4] = {-3.0e38f, -3.0e38f, -3.0e38f, -3.0e38f};
  float l_run[4] = {0.f, 0.f, 0.f, 0.f};

  const int T = CAUSAL ? (qb + 1) : (SS / 64);

  for (int t = 0; t < T; ++t) {
    const int kstart = t * 64;
    // ---- QK^T ----
    f32x4 sacc[4];
#pragma unroll
    for (int nb = 0; nb < 4; ++nb) sacc[nb] = (f32x4){0.f, 0.f, 0.f, 0.f};
#pragma unroll
    for (int nb = 0; nb < 4; ++nb) {
#pragma unroll
      for (int ks = 0; ks < 2; ++ks) {
        bf16x8 kf = *(const bf16x8*)&Km[base + (size_t)(kstart + nb * 16 + l15) * DD + ks * 32 + g * 8];
        sacc[nb] = __builtin_amdgcn_mfma_f32_16x16x32_bf16(qf[ks], kf, sacc[nb], 0, 0, 0);
      }
    }
    // ---- scale + mask (registers) ----
#pragma unroll
    for (int nb = 0; nb < 4; ++nb) {
      int colg = kstart + nb * 16 + l15;
#pragma unroll
      for (int r = 0; r < 4; ++r) {
        float sv = sacc[nb][r] * 0.125f;
        if (CAUSAL && colg > qstart + wid * 16 + g * 4 + r) sv = -3.0e38f;
        sacc[nb][r] = sv;
      }
    }
    // ---- per-row online softmax (16-lane group reduce) ----
    float resc[4];
#pragma unroll
    for (int r = 0; r < 4; ++r) {
      float mx = fmaxf(fmaxf(sacc[0][r], sacc[1][r]), fmaxf(sacc[2][r], sacc[3][r]));
      mx = fmaxf(mx, __shfl_xor(mx, 1));
      mx = fmaxf(mx, __shfl_xor(mx, 2));
      mx = fmaxf(mx, __shfl_xor(mx, 4));
      mx = fmaxf(mx, __shfl_xor(mx, 8));
      float mnew = fmaxf(m_run[r], mx);
      float s = 0.f;
#pragma unroll
      for (int nb = 0; nb < 4; ++nb) {
        float e = __expf(sacc[nb][r] - mnew);
        sacc[nb][r] = e; s += e;
      }
      s += __shfl_xor(s, 1);
      s += __shfl_xor(s, 2);
      s += __shfl_xor(s, 4);
      s += __shfl_xor(s, 8);
      resc[r] = __expf(m_run[r] - mnew);
      l_run[r] = l_run[r] * resc[r] + s;
      m_run[r] = mnew;
    }
    // ---- P: C-layout -> A-frag via per-wave LDS (pad 72) ----
#pragma unroll
    for (int r = 0; r < 4; ++r)
#pragma unroll
      for (int nb = 0; nb < 4; ++nb)
        psw[(g * 4 + r) * 72 + nb * 16 + l15] = f2bf(sacc[nb][r]);
    // rescale O
#pragma unroll
    for (int nb = 0; nb < 4; ++nb)
#pragma unroll
      for (int r = 0; r < 4; ++r) oacc[nb][r] *= resc[r];
    // ---- PV ----
    bf16x8 pf[2];
#pragma unroll
    for (int ks = 0; ks < 2; ++ks)
      pf[ks] = *(const bf16x8*)&psw[l15 * 72 + ks * 32 + g * 8];
#pragma unroll
    for (int nb = 0; nb < 4; ++nb) {
#pragma unroll
      for (int ks = 0; ks < 2; ++ks) {
        bf16x8 vf = *(const bf16x8*)&Vt[vtbase + (size_t)(nb * 16 + l15) * SS + kstart + ks * 32 + g * 8];
        oacc[nb] = __builtin_amdgcn_mfma_f32_16x16x32_bf16(pf[ks], vf, oacc[nb], 0, 0, 0);
      }
    }
  }
#pragma unroll
  for (int nb = 0; nb < 4; ++nb) {
#pragma unroll
    for (int r = 0; r < 4; ++r) {
      float inv = 1.f / l_run[r];
      Om[base + (size_t)(qstart + wid * 16 + g * 4 + r) * DD + nb * 16 + l15] =
          f2bf(oacc[nb][r] * inv);
    }
  }
}

// ---------------------------------------------------------------------------
// LayerNorm(a + b) * g + beta ; one wave per row of 512.
__global__ __launch_bounds__(256)
void ln_kernel(const u16* __restrict__ A, const u16* __restrict__ Bv,
               const float* __restrict__ gamma, const float* __restrict__ beta,
               u16* __restrict__ out_bf, float* __restrict__ out_f32) {
  const int row = blockIdx.x * 4 + (threadIdx.x >> 6);
  const int lane = threadIdx.x & 63;
  uint4 av = *(const uint4*)&A[(size_t)row * DD + lane * 8];
  uint4 bv = *(const uint4*)&Bv[(size_t)row * DD + lane * 8];
  const u16* au = (const u16*)&av;
  const u16* bu = (const u16*)&bv;
  float z[8], s = 0.f, s2 = 0.f;
#pragma unroll
  for (int j = 0; j < 8; ++j) {
    float x = bf2f(au[j]) + bf2f(bu[j]);
    z[j] = x; s += x; s2 += x * x;
  }
#pragma unroll
  for (int off = 1; off < 64; off <<= 1) {
    s += __shfl_xor(s, off);
    s2 += __shfl_xor(s2, off);
  }
  float mean = s * (1.f / 512.f);
  float var = s2 * (1.f / 512.f) - mean * mean;
  float rs = rsqrtf(var + 1e-5f);
  union { u16 us[8]; uint4 v; } pk;
#pragma unroll
  for (int j = 0; j < 8; ++j) {
    float o = (z[j] - mean) * rs * gamma[lane * 8 + j] + beta[lane * 8 + j];
    pk.us[j] = f2bf(o);
    if (out_f32) out_f32[(size_t)row * DD + lane * 8 + j] = o;
  }
  *(uint4*)&out_bf[(size_t)row * DD + lane * 8] = pk.v;
}

// ---------------------------------------------------------------------------
extern "C" void kernel_launch(void* const* d_in, const int* in_sizes, int n_in,
                              void* d_out, int out_size, void* d_ws, size_t ws_size,
                              hipStream_t stream) {
  const float* x   = (const float*)d_in[0];
  const float* enc = (const float*)d_in[1];
  const float* sa_w[4] = {(const float*)d_in[2], (const float*)d_in[4], (const float*)d_in[6], (const float*)d_in[8]};
  const float* sa_b[4] = {(const float*)d_in[3], (const float*)d_in[5], (const float*)d_in[7], (const float*)d_in[9]};
  const float* ca_w[4] = {(const float*)d_in[10], (const float*)d_in[12], (const float*)d_in[14], (const float*)d_in[16]};
  const float* ca_b[4] = {(const float*)d_in[11], (const float*)d_in[13], (const float*)d_in[15], (const float*)d_in[17]};
  const float* ln_g[3] = {(const float*)d_in[18], (const float*)d_in[20], (const float*)d_in[22]};
  const float* ln_b[3] = {(const float*)d_in[19], (const float*)d_in[21], (const float*)d_in[23]};
  const float* ffw1 = (const float*)d_in[24];
  const float* ffb1 = (const float*)d_in[25];
  const float* ffw2 = (const float*)d_in[26];
  const float* ffb2 = (const float*)d_in[27];

  char* ws = (char*)d_ws;
  size_t o = 0;
  auto take = [&](size_t bytes) {
    void* p = ws + o;
    o += (bytes + 255) & ~(size_t)255;
    return p;
  };
  u16* wT[10];
  for (int i = 0; i < 8; ++i) wT[i] = (u16*)take((size_t)LCOUNT * 512 * 512 * 2);
  wT[8] = (u16*)take((size_t)LCOUNT * 512 * 2048 * 2);   // w1t [F][D]
  wT[9] = (u16*)take((size_t)LCOUNT * 2048 * 512 * 2);   // w2t [D][F]
  u16* Hb  = (u16*)take((size_t)MM * 512 * 2);
  u16* Eb  = (u16*)take((size_t)MM * 512 * 2);
  u16* Qb  = (u16*)take((size_t)MM * 512 * 2);
  u16* Kb  = (u16*)take((size_t)MM * 512 * 2);
  u16* Vb  = (u16*)take((size_t)MM * 512 * 2);
  u16* Ab  = (u16*)take((size_t)MM * 512 * 2);
  u16* Pb  = (u16*)take((size_t)MM * 512 * 2);
  u16* X1b = (u16*)take((size_t)MM * 512 * 2);
  u16* Yb  = (u16*)take((size_t)MM * 512 * 2);
  u16* Fb  = (u16*)take((size_t)MM * 2048 * 2);
  u16* Vtb = Fb;  // Vt scratch reuses FFN buffer (dead during attention)

  f2bf_kernel<<<2048, 256, 0, stream>>>(x, Hb, MM * 512);
  f2bf_kernel<<<2048, 256, 0, stream>>>(enc, Eb, MM * 512);
  for (int i = 0; i < 4; ++i) {
    wtrans<<<dim3(8, 8, LCOUNT), 256, 0, stream>>>(sa_w[i], wT[i], 512, 512);
    wtrans<<<dim3(8, 8, LCOUNT), 256, 0, stream>>>(ca_w[i], wT[4 + i], 512, 512);
  }
  wtrans<<<dim3(32, 8, LCOUNT), 256, 0, stream>>>(ffw1, wT[8], 512, 2048);
  wtrans<<<dim3(8, 32, LCOUNT), 256, 0, stream>>>(ffw2, wT[9], 2048, 512);

  for (int l = 0; l < LCOUNT; ++l) {
    const size_t w512 = (size_t)l * 512 * 512;
    const size_t wff = (size_t)l * 512 * 2048;
    // --- masked self-attention ---
    gemm_bt<64, false><<<dim3(4, MM / 64), 256, 0, stream>>>(Hb, wT[0] + w512, sa_b[0] + l * 512, Qb, 512, 512);
    gemm_bt<64, false><<<dim3(4, MM / 64), 256, 0, stream>>>(Hb, wT[1] + w512, sa_b[1] + l * 512, Kb, 512, 512);
    gemm_bt<64, false><<<dim3(4, MM / 64), 256, 0, stream>>>(Hb, wT[2] + w512, sa_b[2] + l * 512, Vb, 512, 512);
    vtrans<<<dim3(32, 8, 4), 256, 0, stream>>>(Vb, Vtb);
    attn_kernel<true><<<dim3(32, 8, 4), 256, 0, stream>>>(Qb, Kb, Vtb, Ab);
    gemm_bt<64, false><<<dim3(4, MM / 64), 256, 0, stream>>>(Ab, wT[3] + w512, sa_b[3] + l * 512, Pb, 512, 512);
    ln_kernel<<<MM / 4, 256, 0, stream>>>(Hb, Pb, ln_g[0] + l * 512, ln_b[0] + l * 512, X1b, nullptr);
    // --- cross-attention (residual from block input Hb, per source) ---
    gemm_bt<64, false><<<dim3(4, MM / 64), 256, 0, stream>>>(X1b, wT[4] + w512, ca_b[0] + l * 512, Qb, 512, 512);
    gemm_bt<64, false><<<dim3(4, MM / 64), 256, 0, stream>>>(Eb, wT[5] + w512, ca_b[1] + l * 512, Kb, 512, 512);
    gemm_bt<64, false><<<dim3(4, MM / 64), 256, 0, stream>>>(Eb, wT[6] + w512, ca_b[2] + l * 512, Vb, 512, 512);
    vtrans<<<dim3(32, 8, 4), 256, 0, stream>>>(Vb, Vtb);
    attn_kernel<false><<<dim3(32, 8, 4), 256, 0, stream>>>(Qb, Kb, Vtb, Ab);
    gemm_bt<64, false><<<dim3(4, MM / 64), 256, 0, stream>>>(Ab, wT[7] + w512, ca_b[3] + l * 512, Pb, 512, 512);
    ln_kernel<<<MM / 4, 256, 0, stream>>>(Hb, Pb, ln_g[1] + l * 512, ln_b[1] + l * 512, Yb, nullptr);
    // --- FFN (residual from X1b, per source) ---
    gemm_bt<128, true><<<dim3(16, MM / 128), 256, 0, stream>>>(Yb, wT[8] + wff, ffb1 + l * 2048, Fb, 2048, 512);
    gemm_bt<64, false><<<dim3(4, MM / 64), 256, 0, stream>>>(Fb, wT[9] + wff, ffb2 + l * 512, Pb, 512, 2048);
    ln_kernel<<<MM / 4, 256, 0, stream>>>(X1b, Pb, ln_g[2] + l * 512, ln_b[2] + l * 512, Hb,
                                          (l == LCOUNT - 1) ? (float*)d_out : nullptr);
  }
}

// Round 3
// 2667.979 us; speedup vs baseline: 1.5309x; 1.5309x over previous
//
#include <hip/hip_runtime.h>
#include <stdint.h>

#define LCOUNT 6
#define BB 4
#define SS 2048
#define DD 512
#define HH 8
#define DKK 64
#define FFDIM 2048
#define MM (BB*SS)  // 8192 rows

typedef __attribute__((ext_vector_type(8))) __bf16 bf16x8;
typedef __attribute__((ext_vector_type(4))) float f32x4;
typedef unsigned short u16;

__device__ __forceinline__ u16 f2bf(float f) {
  union { float f; uint32_t u; } v; v.f = f;
  uint32_t r = v.u + 0x7FFFu + ((v.u >> 16) & 1u);
  return (u16)(r >> 16);
}
__device__ __forceinline__ float bf2f(u16 u) {
  union { uint32_t u; float f; } v; v.u = ((uint32_t)u) << 16;
  return v.f;
}

__device__ __forceinline__ void gload_lds16(const u16* gsrc, u16* ldst) {
  __builtin_amdgcn_global_load_lds((const __attribute__((address_space(1))) char*)gsrc,
                                   (__attribute__((address_space(3))) char*)ldst, 16, 0, 0);
}

// ---------------------------------------------------------------------------
// fp32 -> bf16 elementwise convert (n divisible by 8)
__global__ __launch_bounds__(256) void f2bf_kernel(const float* __restrict__ in,
                                                   u16* __restrict__ outp, int n) {
  int i = (blockIdx.x * 256 + threadIdx.x) * 8;
  if (i >= n) return;
  float4 a = *(const float4*)&in[i];
  float4 b = *(const float4*)&in[i + 4];
  union { u16 us[8]; uint4 v; } pk;
  pk.us[0] = f2bf(a.x); pk.us[1] = f2bf(a.y); pk.us[2] = f2bf(a.z); pk.us[3] = f2bf(a.w);
  pk.us[4] = f2bf(b.x); pk.us[5] = f2bf(b.y); pk.us[6] = f2bf(b.z); pk.us[7] = f2bf(b.w);
  *(uint4*)&outp[i] = pk.v;
}

// ---------------------------------------------------------------------------
// W [K][N] fp32  ->  Wt [N][K] bf16   (per layer, blockIdx.z = layer)
__global__ __launch_bounds__(256) void wtrans(const float* __restrict__ W,
                                              u16* __restrict__ Wt, int K_, int N_) {
  __shared__ float tile[64 * 65];
  const int l = blockIdx.z;
  const float* Wl = W + (size_t)l * K_ * N_;
  u16* Wtl = Wt + (size_t)l * K_ * N_;
  const int n0 = blockIdx.x * 64, k0 = blockIdx.y * 64;
  const int tid = threadIdx.x;
  const int r = tid >> 2, c4 = (tid & 3) * 16;
#pragma unroll
  for (int j = 0; j < 16; j += 4) {
    float4 v = *(const float4*)&Wl[(size_t)(k0 + r) * N_ + n0 + c4 + j];
    tile[r * 65 + c4 + j + 0] = v.x;
    tile[r * 65 + c4 + j + 1] = v.y;
    tile[r * 65 + c4 + j + 2] = v.z;
    tile[r * 65 + c4 + j + 3] = v.w;
  }
  __syncthreads();
  const int nr = tid >> 2, kc = (tid & 3) * 16;
#pragma unroll
  for (int half = 0; half < 2; ++half) {
    union { u16 us[8]; uint4 v; } pk;
#pragma unroll
    for (int e = 0; e < 8; ++e) pk.us[e] = f2bf(tile[(kc + half * 8 + e) * 65 + nr]);
    *(uint4*)&Wtl[(size_t)(n0 + nr) * K_ + k0 + kc + half * 8] = pk.v;
  }
}

// ---------------------------------------------------------------------------
// V [B*S][D] bf16 (head h cols)  ->  Vt [B][H][DK][S] bf16
__global__ __launch_bounds__(256)
void vtrans(const u16* __restrict__ V, u16* __restrict__ Vt) {
  __shared__ u16 tile[64 * 64];
  const int st = blockIdx.x, h = blockIdx.y, b = blockIdx.z;
  const int tid = threadIdx.x;
  const int s_r = tid & 63;
#pragma unroll
  for (int j = 0; j < 2; ++j) {
    int chunk = (tid >> 6) + 4 * j;
    int slot = chunk ^ (s_r & 7);
    uint4 v = *(const uint4*)&V[(size_t)(b * SS + st * 64 + s_r) * DD + h * DKK + chunk * 8];
    *(uint4*)&tile[s_r * 64 + slot * 8] = v;
  }
  __syncthreads();
  const int d = tid & 63, sc = tid >> 6;
  union { u16 us[16]; uint4 v[2]; } pk;
#pragma unroll
  for (int e = 0; e < 16; ++e) {
    int s = sc * 16 + e;
    pk.us[e] = tile[s * 64 + (((d >> 3) ^ (s & 7)) * 8) + (d & 7)];
  }
  u16* dst = &Vt[((size_t)(b * HH + h) * DKK + d) * SS + st * 64 + sc * 16];
  *(uint4*)&dst[0] = pk.v[0];
  *(uint4*)&dst[8] = pk.v[1];
}

// ---------------------------------------------------------------------------
// GEMM: C[M,N] = A[M,K] @ W[K,N] + bias, W given transposed Wt[N][K].
template <int BMT, bool RELU>
__global__ __launch_bounds__(256)
void gemm_bt(const u16* __restrict__ A, const u16* __restrict__ Bt,
             const float* __restrict__ bias, u16* __restrict__ C,
             int N_, int K_) {
  constexpr int MR = BMT / 32;  // m-fragments per wave
  __shared__ u16 As[BMT * 64];
  __shared__ u16 Bs[128 * 64];
  const int tid = threadIdx.x;
  const int wid = tid >> 6, lane = tid & 63;
  const int l15 = lane & 15, g = lane >> 4;
  const int wr = wid >> 1, wc = wid & 1;
  const int brow = blockIdx.y * BMT;
  const int bcol = blockIdx.x * 128;

  f32x4 acc[MR][4];
#pragma unroll
  for (int m = 0; m < MR; ++m)
#pragma unroll
    for (int n = 0; n < 4; ++n) acc[m][n] = (f32x4){0.f, 0.f, 0.f, 0.f};

  for (int kt = 0; kt < K_; kt += 64) {
#pragma unroll
    for (int r = 0; r < BMT / 32; ++r) {
      int row = r * 32 + wid * 8 + (lane >> 3);
      int slot = (lane & 7) ^ (row & 7);
      gload_lds16(A + (size_t)(brow + row) * K_ + kt + slot * 8,
                  &As[r * 2048 + wid * 512]);
    }
#pragma unroll
    for (int r = 0; r < 4; ++r) {
      int row = r * 32 + wid * 8 + (lane >> 3);
      int slot = (lane & 7) ^ (row & 7);
      gload_lds16(Bt + (size_t)(bcol + row) * K_ + kt + slot * 8,
                  &Bs[r * 2048 + wid * 512]);
    }
    __syncthreads();
#pragma unroll
    for (int ks = 0; ks < 2; ++ks) {
      bf16x8 af[MR], bfr[4];
#pragma unroll
      for (int m = 0; m < MR; ++m) {
        int row = wr * (BMT / 2) + m * 16 + l15;
        int slot = (ks * 4 + g) ^ (row & 7);
        af[m] = *(const bf16x8*)&As[row * 64 + slot * 8];
      }
#pragma unroll
      for (int n = 0; n < 4; ++n) {
        int row = wc * 64 + n * 16 + l15;
        int slot = (ks * 4 + g) ^ (row & 7);
        bfr[n] = *(const bf16x8*)&Bs[row * 64 + slot * 8];
      }
#pragma unroll
      for (int m = 0; m < MR; ++m)
#pragma unroll
        for (int n = 0; n < 4; ++n)
          acc[m][n] = __builtin_amdgcn_mfma_f32_16x16x32_bf16(af[m], bfr[n], acc[m][n], 0, 0, 0);
    }
    __syncthreads();
  }
#pragma unroll
  for (int n = 0; n < 4; ++n) {
    int col = bcol + wc * 64 + n * 16 + l15;
    float bv = bias ? bias[col] : 0.f;
#pragma unroll
    for (int m = 0; m < MR; ++m) {
#pragma unroll
      for (int r = 0; r < 4; ++r) {
        int rowg = brow + wr * (BMT / 2) + m * 16 + g * 4 + r;
        float v = acc[m][n][r] + bv;
        if (RELU) v = fmaxf(v, 0.f);
        C[(size_t)rowg * N_ + col] = f2bf(v);
      }
    }
  }
}

// ---------------------------------------------------------------------------
// Flash attention: block = (qblock=64, head, batch), 4 waves; wave owns 16
// q-rows. K and V tiles LDS-staged via global_load_lds, double-buffered,
// ONE barrier per tile; stage(t+1) issued before compute(t) so the barrier's
// vmcnt(0) drain is free. Softmax in registers (16-lane shfl reduce).
// P transposed via per-wave XOR-swizzled LDS (stride 64).
template <bool CAUSAL>
__global__ __launch_bounds__(256, 4)
void attn_kernel(const u16* __restrict__ Qm, const u16* __restrict__ Km,
                 const u16* __restrict__ Vt, u16* __restrict__ Om) {
  __shared__ u16 Ks[2][64 * 64];
  __shared__ u16 Vs[2][64 * 64];
  __shared__ u16 Ps[4][16 * 64];
  const int qb = blockIdx.x, h = blockIdx.y, b = blockIdx.z;
  const int tid = threadIdx.x, wid = tid >> 6, lane = tid & 63;
  const int l15 = lane & 15, g = lane >> 4;
  const int qstart = qb * 64;
  const size_t base = ((size_t)b * SS) * DD + h * DKK;
  const size_t vtbase = (size_t)(b * HH + h) * DKK * SS;
  u16* psw = &Ps[wid][0];

  const int srow = wid * 8 + (lane >> 3);  // staging row within a 32-row half
  const int sslot = lane & 7;

  bf16x8 qf[2];
#pragma unroll
  for (int ks = 0; ks < 2; ++ks)
    qf[ks] = *(const bf16x8*)&Qm[base + (size_t)(qstart + wid * 16 + l15) * DD + ks * 32 + g * 8];

  f32x4 oacc[4];
#pragma unroll
  for (int nb = 0; nb < 4; ++nb) oacc[nb] = (f32x4){0.f, 0.f, 0.f, 0.f};
  float m_run[4] = {-3.0e38f, -3.0e38f, -3.0e38f, -3.0e38f};
  float l_run[4] = {0.f, 0.f, 0.f, 0.f};

  const int T = CAUSAL ? (qb + 1) : (SS / 64);

  // prologue: stage tile 0
#pragma unroll
  for (int r = 0; r < 2; ++r) {
    int row = r * 32 + srow;
    int slot = sslot ^ (row & 7);
    gload_lds16(Km + base + (size_t)row * DD + slot * 8, &Ks[0][r * 2048 + wid * 512]);
    gload_lds16(Vt + vtbase + (size_t)row * SS + slot * 8, &Vs[0][r * 2048 + wid * 512]);
  }
  __syncthreads();

  int cur = 0;
  for (int t = 0; t < T; ++t) {
    const int kstart = t * 64;
    // stage t+1 into the other buffer (drained by this tile's end barrier)
    if (t + 1 < T) {
#pragma unroll
      for (int r = 0; r < 2; ++r) {
        int row = r * 32 + srow;
        int slot = sslot ^ (row & 7);
        gload_lds16(Km + base + (size_t)(kstart + 64 + row) * DD + slot * 8,
                    &Ks[cur ^ 1][r * 2048 + wid * 512]);
        gload_lds16(Vt + vtbase + (size_t)row * SS + kstart + 64 + slot * 8,
                    &Vs[cur ^ 1][r * 2048 + wid * 512]);
      }
    }
    // ---- QK^T from LDS ----
    f32x4 sacc[4];
#pragma unroll
    for (int nb = 0; nb < 4; ++nb) sacc[nb] = (f32x4){0.f, 0.f, 0.f, 0.f};
#pragma unroll
    for (int nb = 0; nb < 4; ++nb) {
      int row = nb * 16 + l15;
#pragma unroll
      for (int ks = 0; ks < 2; ++ks) {
        bf16x8 kf = *(const bf16x8*)&Ks[cur][row * 64 + (((ks * 4 + g) ^ (row & 7)) * 8)];
        sacc[nb] = __builtin_amdgcn_mfma_f32_16x16x32_bf16(qf[ks], kf, sacc[nb], 0, 0, 0);
      }
    }
    // ---- scale + mask ----
#pragma unroll
    for (int nb = 0; nb < 4; ++nb) {
      int colg = kstart + nb * 16 + l15;
#pragma unroll
      for (int r = 0; r < 4; ++r) {
        float sv = sacc[nb][r] * 0.125f;
        if (CAUSAL && colg > qstart + wid * 16 + g * 4 + r) sv = -3.0e38f;
        sacc[nb][r] = sv;
      }
    }
    // ---- per-row online softmax ----
    float resc[4];
#pragma unroll
    for (int r = 0; r < 4; ++r) {
      float mx = fmaxf(fmaxf(sacc[0][r], sacc[1][r]), fmaxf(sacc[2][r], sacc[3][r]));
      mx = fmaxf(mx, __shfl_xor(mx, 1));
      mx = fmaxf(mx, __shfl_xor(mx, 2));
      mx = fmaxf(mx, __shfl_xor(mx, 4));
      mx = fmaxf(mx, __shfl_xor(mx, 8));
      float mnew = fmaxf(m_run[r], mx);
      float s = 0.f;
#pragma unroll
      for (int nb = 0; nb < 4; ++nb) {
        float e = __expf(sacc[nb][r] - mnew);
        sacc[nb][r] = e; s += e;
      }
      s += __shfl_xor(s, 1);
      s += __shfl_xor(s, 2);
      s += __shfl_xor(s, 4);
      s += __shfl_xor(s, 8);
      resc[r] = __expf(m_run[r] - mnew);
      l_run[r] = l_run[r] * resc[r] + s;
      m_run[r] = mnew;
    }
    // ---- P pack: C-layout -> swizzled LDS (row = local q, col = k) ----
#pragma unroll
    for (int r = 0; r < 4; ++r) {
      int row = g * 4 + r;
#pragma unroll
      for (int nb = 0; nb < 4; ++nb) {
        int chunk = 2 * nb + (l15 >> 3);
        psw[row * 64 + ((chunk ^ (row & 7)) * 8) + (l15 & 7)] = f2bf(sacc[nb][r]);
      }
    }
    // rescale O
#pragma unroll
    for (int nb = 0; nb < 4; ++nb)
#pragma unroll
      for (int r = 0; r < 4; ++r) oacc[nb][r] *= resc[r];
    // ---- PV from LDS ----
    bf16x8 pf[2];
#pragma unroll
    for (int ks = 0; ks < 2; ++ks)
      pf[ks] = *(const bf16x8*)&psw[l15 * 64 + (((ks * 4 + g) ^ (l15 & 7)) * 8)];
#pragma unroll
    for (int nb = 0; nb < 4; ++nb) {
      int row = nb * 16 + l15;  // d-row in Vs
#pragma unroll
      for (int ks = 0; ks < 2; ++ks) {
        bf16x8 vf = *(const bf16x8*)&Vs[cur][row * 64 + (((ks * 4 + g) ^ (row & 7)) * 8)];
        oacc[nb] = __builtin_amdgcn_mfma_f32_16x16x32_bf16(pf[ks], vf, oacc[nb], 0, 0, 0);
      }
    }
    __syncthreads();
    cur ^= 1;
  }
#pragma unroll
  for (int nb = 0; nb < 4; ++nb) {
#pragma unroll
    for (int r = 0; r < 4; ++r) {
      float inv = 1.f / l_run[r];
      Om[base + (size_t)(qstart + wid * 16 + g * 4 + r) * DD + nb * 16 + l15] =
          f2bf(oacc[nb][r] * inv);
    }
  }
}

// ---------------------------------------------------------------------------
// LayerNorm(a + b) * g + beta ; one wave per row of 512.
__global__ __launch_bounds__(256)
void ln_kernel(const u16* __restrict__ A, const u16* __restrict__ Bv,
               const float* __restrict__ gamma, const float* __restrict__ beta,
               u16* __restrict__ out_bf, float* __restrict__ out_f32) {
  const int row = blockIdx.x * 4 + (threadIdx.x >> 6);
  const int lane = threadIdx.x & 63;
  uint4 av = *(const uint4*)&A[(size_t)row * DD + lane * 8];
  uint4 bv = *(const uint4*)&Bv[(size_t)row * DD + lane * 8];
  const u16* au = (const u16*)&av;
  const u16* bu = (const u16*)&bv;
  float z[8], s = 0.f, s2 = 0.f;
#pragma unroll
  for (int j = 0; j < 8; ++j) {
    float x = bf2f(au[j]) + bf2f(bu[j]);
    z[j] = x; s += x; s2 += x * x;
  }
#pragma unroll
  for (int off = 1; off < 64; off <<= 1) {
    s += __shfl_xor(s, off);
    s2 += __shfl_xor(s2, off);
  }
  float mean = s * (1.f / 512.f);
  float var = s2 * (1.f / 512.f) - mean * mean;
  float rs = rsqrtf(var + 1e-5f);
  union { u16 us[8]; uint4 v; } pk;
#pragma unroll
  for (int j = 0; j < 8; ++j) {
    float o = (z[j] - mean) * rs * gamma[lane * 8 + j] + beta[lane * 8 + j];
    pk.us[j] = f2bf(o);
    if (out_f32) out_f32[(size_t)row * DD + lane * 8 + j] = o;
  }
  *(uint4*)&out_bf[(size_t)row * DD + lane * 8] = pk.v;
}

// ---------------------------------------------------------------------------
extern "C" void kernel_launch(void* const* d_in, const int* in_sizes, int n_in,
                              void* d_out, int out_size, void* d_ws, size_t ws_size,
                              hipStream_t stream) {
  const float* x   = (const float*)d_in[0];
  const float* enc = (const float*)d_in[1];
  const float* sa_w[4] = {(const float*)d_in[2], (const float*)d_in[4], (const float*)d_in[6], (const float*)d_in[8]};
  const float* sa_b[4] = {(const float*)d_in[3], (const float*)d_in[5], (const float*)d_in[7], (const float*)d_in[9]};
  const float* ca_w[4] = {(const float*)d_in[10], (const float*)d_in[12], (const float*)d_in[14], (const float*)d_in[16]};
  const float* ca_b[4] = {(const float*)d_in[11], (const float*)d_in[13], (const float*)d_in[15], (const float*)d_in[17]};
  const float* ln_g[3] = {(const float*)d_in[18], (const float*)d_in[20], (const float*)d_in[22]};
  const float* ln_b[3] = {(const float*)d_in[19], (const float*)d_in[21], (const float*)d_in[23]};
  const float* ffw1 = (const float*)d_in[24];
  const float* ffb1 = (const float*)d_in[25];
  const float* ffw2 = (const float*)d_in[26];
  const float* ffb2 = (const float*)d_in[27];

  char* ws = (char*)d_ws;
  size_t o = 0;
  auto take = [&](size_t bytes) {
    void* p = ws + o;
    o += (bytes + 255) & ~(size_t)255;
    return p;
  };
  u16* wT[10];
  for (int i = 0; i < 8; ++i) wT[i] = (u16*)take((size_t)LCOUNT * 512 * 512 * 2);
  wT[8] = (u16*)take((size_t)LCOUNT * 512 * 2048 * 2);   // w1t [F][D]
  wT[9] = (u16*)take((size_t)LCOUNT * 2048 * 512 * 2);   // w2t [D][F]
  u16* Hb  = (u16*)take((size_t)MM * 512 * 2);
  u16* Eb  = (u16*)take((size_t)MM * 512 * 2);
  u16* Qb  = (u16*)take((size_t)MM * 512 * 2);
  u16* Kb  = (u16*)take((size_t)MM * 512 * 2);
  u16* Vb  = (u16*)take((size_t)MM * 512 * 2);
  u16* Ab  = (u16*)take((size_t)MM * 512 * 2);
  u16* Pb  = (u16*)take((size_t)MM * 512 * 2);
  u16* X1b = (u16*)take((size_t)MM * 512 * 2);
  u16* Yb  = (u16*)take((size_t)MM * 512 * 2);
  u16* Fb  = (u16*)take((size_t)MM * 2048 * 2);
  u16* Vtb = Fb;  // Vt scratch reuses FFN buffer (dead during attention)

  f2bf_kernel<<<2048, 256, 0, stream>>>(x, Hb, MM * 512);
  f2bf_kernel<<<2048, 256, 0, stream>>>(enc, Eb, MM * 512);
  for (int i = 0; i < 4; ++i) {
    wtrans<<<dim3(8, 8, LCOUNT), 256, 0, stream>>>(sa_w[i], wT[i], 512, 512);
    wtrans<<<dim3(8, 8, LCOUNT), 256, 0, stream>>>(ca_w[i], wT[4 + i], 512, 512);
  }
  wtrans<<<dim3(32, 8, LCOUNT), 256, 0, stream>>>(ffw1, wT[8], 512, 2048);
  wtrans<<<dim3(8, 32, LCOUNT), 256, 0, stream>>>(ffw2, wT[9], 2048, 512);

  for (int l = 0; l < LCOUNT; ++l) {
    const size_t w512 = (size_t)l * 512 * 512;
    const size_t wff = (size_t)l * 512 * 2048;
    // --- masked self-attention ---
    gemm_bt<64, false><<<dim3(4, MM / 64), 256, 0, stream>>>(Hb, wT[0] + w512, sa_b[0] + l * 512, Qb, 512, 512);
    gemm_bt<64, false><<<dim3(4, MM / 64), 256, 0, stream>>>(Hb, wT[1] + w512, sa_b[1] + l * 512, Kb, 512, 512);
    gemm_bt<64, false><<<dim3(4, MM / 64), 256, 0, stream>>>(Hb, wT[2] + w512, sa_b[2] + l * 512, Vb, 512, 512);
    vtrans<<<dim3(32, 8, 4), 256, 0, stream>>>(Vb, Vtb);
    attn_kernel<true><<<dim3(32, 8, 4), 256, 0, stream>>>(Qb, Kb, Vtb, Ab);
    gemm_bt<64, false><<<dim3(4, MM / 64), 256, 0, stream>>>(Ab, wT[3] + w512, sa_b[3] + l * 512, Pb, 512, 512);
    ln_kernel<<<MM / 4, 256, 0, stream>>>(Hb, Pb, ln_g[0] + l * 512, ln_b[0] + l * 512, X1b, nullptr);
    // --- cross-attention (residual from block input Hb, per source) ---
    gemm_bt<64, false><<<dim3(4, MM / 64), 256, 0, stream>>>(X1b, wT[4] + w512, ca_b[0] + l * 512, Qb, 512, 512);
    gemm_bt<64, false><<<dim3(4, MM / 64), 256, 0, stream>>>(Eb, wT[5] + w512, ca_b[1] + l * 512, Kb, 512, 512);
    gemm_bt<64, false><<<dim3(4, MM / 64), 256, 0, stream>>>(Eb, wT[6] + w512, ca_b[2] + l * 512, Vb, 512, 512);
    vtrans<<<dim3(32, 8, 4), 256, 0, stream>>>(Vb, Vtb);
    attn_kernel<false><<<dim3(32, 8, 4), 256, 0, stream>>>(Qb, Kb, Vtb, Ab);
    gemm_bt<64, false><<<dim3(4, MM / 64), 256, 0, stream>>>(Ab, wT[7] + w512, ca_b[3] + l * 512, Pb, 512, 512);
    ln_kernel<<<MM / 4, 256, 0, stream>>>(Hb, Pb, ln_g[1] + l * 512, ln_b[1] + l * 512, Yb, nullptr);
    // --- FFN (residual from X1b, per source) ---
    gemm_bt<128, true><<<dim3(16, MM / 128), 256, 0, stream>>>(Yb, wT[8] + wff, ffb1 + l * 2048, Fb, 2048, 512);
    gemm_bt<64, false><<<dim3(4, MM / 64), 256, 0, stream>>>(Fb, wT[9] + wff, ffb2 + l * 512, Pb, 512, 2048);
    ln_kernel<<<MM / 4, 256, 0, stream>>>(X1b, Pb, ln_g[2] + l * 512, ln_b[2] + l * 512, Hb,
                                          (l == LCOUNT - 1) ? (float*)d_out : nullptr);
  }
}